// Round 1
// baseline (1627.095 us; speedup 1.0000x reference)
//
#include <hip/hip_runtime.h>

typedef _Float16 f16;
typedef _Float16 f16x4 __attribute__((ext_vector_type(4)));
typedef _Float16 f16x8 __attribute__((ext_vector_type(8)));
typedef float f32x4 __attribute__((ext_vector_type(4)));

#define B_ 64
#define TIN 1000
#define CIN 4
#define F_ 320
#define KW 26
#define TCONV 975
#define TPOOL 75
#define H_ 320
#define G3 960
#define FLAT 48000
#define D1 2000
#define D2 301

// ---------------- prep kernels ----------------

__global__ void k_prep_in(const float* __restrict__ inp, f16* __restrict__ o) {
    int i = blockIdx.x * 256 + threadIdx.x;
    if (i < B_ * TIN * CIN) o[i] = (f16)inp[i];
}

// conv weights -> fragment-order swizzle. layout [nt(20)][kf(4)][lane(64)][e(8)]
// frag element: k = kf*32 + 8*(l>>4) + e ; kk = k>>2, c = k&3 ; f = nt*16 + (l&15)
__global__ void k_prep_w(const float* __restrict__ w, f16* __restrict__ o) {
    int i = blockIdx.x * 256 + threadIdx.x;
    if (i >= 20 * 4 * 64 * 8) return;
    int e = i & 7, l = (i >> 3) & 63, t1 = i >> 9;
    int kf = t1 & 3, nt = t1 >> 2;
    int k = kf * 32 + 8 * (l >> 4) + e;
    int kk = k >> 2, c = k & 3, f = nt * 16 + (l & 15);
    o[i] = (f16)((kk < KW) ? w[(kk * CIN + c) * F_ + f] : 0.f);
}

// gru kernel / recurrent-kernel swizzle. layout [d(2)][nt(60)][kf(10)][lane(64)][e(8)]
// k = kf*32 + 8*(l>>4) + e (0..319), n = nt*16 + (l&15) (0..959)
__global__ void k_prep_k(const float* __restrict__ fw, const float* __restrict__ bw,
                         f16* __restrict__ o) {
    int i = blockIdx.x * 256 + threadIdx.x;
    if (i >= 2 * 60 * 10 * 64 * 8) return;
    int e = i & 7, l = (i >> 3) & 63, t1 = i >> 9;
    int kf = t1 % 10; int t2 = t1 / 10;
    int nt = t2 % 60; int d = t2 / 60;
    int k = kf * 32 + 8 * (l >> 4) + e;
    int n = nt * 16 + (l & 15);
    const float* src = d ? bw : fw;
    o[i] = (f16)src[k * G3 + n];
}

// ---------------- conv + relu + pool ----------------
// grid (19 pool-groups-of-4, 64 batch, 5 n-blocks-of-64), 256 thr
__global__ __launch_bounds__(256) void k_conv(const f16* __restrict__ in16,
                                              const f16* __restrict__ wswz,
                                              const float* __restrict__ convb,
                                              f16* __restrict__ xpool) {
    int pg = blockIdx.x, b = blockIdx.y, ntb = blockIdx.z;
    int tid = threadIdx.x, w = tid >> 6, l = tid & 63;
    int g = l >> 4, lm = l & 15;
    __shared__ float convbuf[64 * 72];

    int r = 16 * w + lm;
    int t = pg * 52 + r;
    int tt = t > (TCONV - 1) ? (TCONV - 1) : t;   // rows past 974 are pool-unused garbage

    f32x4 acc[4] = {};
#pragma unroll
    for (int kf = 0; kf < 4; ++kf) {
        int kk0 = kf * 8 + 2 * g;
        int flat = b * 4000 + (tt + kk0) * 4;
        if (flat > B_ * TIN * CIN - 8) flat = B_ * TIN * CIN - 8; // zero-weighted tail
        f16x4 lo = *(const f16x4*)(in16 + flat);
        f16x4 hi = *(const f16x4*)(in16 + flat + 4);
        f16x8 a;
        a[0] = lo[0]; a[1] = lo[1]; a[2] = lo[2]; a[3] = lo[3];
        a[4] = hi[0]; a[5] = hi[1]; a[6] = hi[2]; a[7] = hi[3];
#pragma unroll
        for (int nt = 0; nt < 4; ++nt) {
            int ntg = ntb * 4 + nt;
            f16x8 bf = *(const f16x8*)(wswz + (size_t)((ntg * 4 + kf) * 64 + l) * 8);
            acc[nt] = __builtin_amdgcn_mfma_f32_16x16x32_f16(a, bf, acc[nt], 0, 0, 0);
        }
    }
#pragma unroll
    for (int nt = 0; nt < 4; ++nt) {
        int f = (ntb * 4 + nt) * 16 + lm;
        float cb = convb[f];
#pragma unroll
        for (int j = 0; j < 4; ++j) {
            int row = 16 * w + 4 * g + j;
            float v = acc[nt][j] + cb;
            convbuf[row * 72 + nt * 16 + lm] = v > 0.f ? v : 0.f;
        }
    }
    __syncthreads();
    int pl = tid >> 6, n = tid & 63;
    int p = pg * 4 + pl;
    if (p < TPOOL) {
        float m = 0.f;  // relu'd values are >= 0
#pragma unroll
        for (int q = 0; q < 13; ++q) m = fmaxf(m, convbuf[(pl * 13 + q) * 72 + n]);
        xpool[((size_t)p * B_ + b) * F_ + ntb * 64 + n] = (f16)m;
    }
}

// ---------------- mx = x @ k + bi (+ br for z,r cols) ----------------
// grid (75 t, 15 nb, 2 dir), 256 thr
__global__ __launch_bounds__(256) void k_mx(const f16* __restrict__ xpool,
                                            const f16* __restrict__ kswz,
                                            const float* __restrict__ fwb,
                                            const float* __restrict__ bwb,
                                            float* __restrict__ mx) {
    int t = blockIdx.x, ntb = blockIdx.y, d = blockIdx.z;
    int tid = threadIdx.x, w = tid >> 6, l = tid & 63;
    int g = l >> 4, lm = l & 15;
    int b = 16 * w + lm;

    f16x8 a[10];
    const f16* ap = xpool + ((size_t)t * B_ + b) * F_;
#pragma unroll
    for (int kf = 0; kf < 10; ++kf) a[kf] = *(const f16x8*)(ap + kf * 32 + 8 * g);

    const f16* kp = kswz + (size_t)d * 60 * 10 * 64 * 8;
    const float* gb = d ? bwb : fwb;

    f32x4 acc[4] = {};
#pragma unroll
    for (int kf = 0; kf < 10; ++kf) {
        f16x8 af = a[kf];
#pragma unroll
        for (int nt = 0; nt < 4; ++nt) {
            int ntg = ntb * 4 + nt;
            f16x8 bf = *(const f16x8*)(kp + (size_t)((ntg * 10 + kf) * 64 + l) * 8);
            acc[nt] = __builtin_amdgcn_mfma_f32_16x16x32_f16(af, bf, acc[nt], 0, 0, 0);
        }
    }
    float* op = mx + ((size_t)d * TPOOL + t) * B_ * G3;
#pragma unroll
    for (int nt = 0; nt < 4; ++nt) {
        int n = (ntb * 4 + nt) * 16 + lm;
        float bias = gb[n] + (n < 640 ? gb[G3 + n] : 0.f); // fold bi + (br for z,r only)
#pragma unroll
        for (int j = 0; j < 4; ++j) {
            int bb = 16 * w + 4 * g + j;
            op[(size_t)bb * G3 + n] = acc[nt][j] + bias;
        }
    }
}

// ---------------- GRU recurrence ----------------
// grid 8 = (dir, batch-group-of-16), 1024 thr (16 waves; waves 0..11 do 5 N-tiles each)
__global__ __launch_bounds__(1024) void k_gru(const f16* __restrict__ rkswz,
                                              const float* __restrict__ mx,
                                              const float* __restrict__ fwb,
                                              const float* __restrict__ bwb,
                                              f16* __restrict__ a16) {
    int d = blockIdx.x >> 2, g4 = blockIdx.x & 3;
    int tid = threadIdx.x;
    int w = tid >> 6, l = tid & 63, g = l >> 4, lm = l & 15;
    __shared__ f16 h16[16 * 328];
    __shared__ float h32[16 * 320];
    __shared__ float mi[16 * 964];
    for (int i = tid; i < 16 * 328; i += 1024) h16[i] = (f16)0.f;
    for (int i = tid; i < 16 * 320; i += 1024) h32[i] = 0.f;

    int ub = tid >> 6;   // update: batch (uniform per wave)
    int ul = tid & 63;   // update: unit lane
    const float* gb = d ? bwb : fwb;
    float brh[5];
#pragma unroll
    for (int j = 0; j < 5; ++j) brh[j] = gb[G3 + 640 + ul + 64 * j]; // recurrent bias, h-gate only

    const f16* rkp = rkswz + (size_t)d * 60 * 10 * 64 * 8;
    bool mfma_wave = (w < 12);
    __syncthreads();

    for (int s = 0; s < TPOOL; ++s) {
        int t = d ? (TPOOL - 1 - s) : s;
        // prefetch this step's mx row slices (consumed after barrier)
        const float* mrow = mx + (((size_t)d * TPOOL + t) * B_ + (g4 * 16 + ub)) * G3;
        float pz[5], pr[5], ph[5];
#pragma unroll
        for (int j = 0; j < 5; ++j) {
            int u = ul + 64 * j;
            pz[j] = mrow[u]; pr[j] = mrow[320 + u]; ph[j] = mrow[640 + u];
        }
        if (mfma_wave) {
            f16x8 a[10];
#pragma unroll
            for (int kf = 0; kf < 10; ++kf)
                a[kf] = *(const f16x8*)(&h16[lm * 328 + kf * 32 + 8 * g]);
            f32x4 acc[5] = {};
#pragma unroll
            for (int kf = 0; kf < 10; ++kf) {
                f16x8 af = a[kf];
#pragma unroll
                for (int i = 0; i < 5; ++i) {
                    int nt = w * 5 + i;
                    f16x8 bf = *(const f16x8*)(rkp + (size_t)((nt * 10 + kf) * 64 + l) * 8);
                    acc[i] = __builtin_amdgcn_mfma_f32_16x16x32_f16(af, bf, acc[i], 0, 0, 0);
                }
            }
#pragma unroll
            for (int i = 0; i < 5; ++i) {
                int nt = w * 5 + i;
#pragma unroll
                for (int j = 0; j < 4; ++j)
                    mi[(4 * g + j) * 964 + nt * 16 + lm] = acc[i][j];
            }
        }
        __syncthreads();
        // gate update: thread owns (ub, u) for 5 units
#pragma unroll
        for (int j = 0; j < 5; ++j) {
            int u = ul + 64 * j;
            float miz = mi[ub * 964 + u];
            float mir = mi[ub * 964 + 320 + u];
            float mih = mi[ub * 964 + 640 + u];
            float z = 1.f / (1.f + __expf(-(pz[j] + miz)));
            float rr = 1.f / (1.f + __expf(-(pr[j] + mir)));
            float hhat = ph[j] + rr * (mih + brh[j]);
            float e2 = __expf(2.f * hhat);
            float cand = 1.f - 2.f / (e2 + 1.f);
            float ho = h32[ub * 320 + u];
            float hn = z * ho + (1.f - z) * cand;
            h32[ub * 320 + u] = hn;
            h16[ub * 328 + u] = (f16)hn;
            a16[(size_t)(g4 * 16 + ub) * FLAT + t * 640 + d * 320 + u] = (f16)hn;
        }
        __syncthreads();
    }
}

// ---------------- fc1: part[kc] = A(64,48000-chunk) @ w1-chunk ----------------
// grid (25 k-chunks of 1920, 32 n-blocks of 64), 256 thr
__global__ __launch_bounds__(256) void k_fc1(const f16* __restrict__ a16,
                                             const float* __restrict__ w1,
                                             float* __restrict__ part) {
    int kc = blockIdx.x, ntb = blockIdx.y;
    int tid = threadIdx.x, w = tid >> 6, l = tid & 63;
    int g = l >> 4, lm = l & 15;
    __shared__ f16 bstage[64 * 40];
    int n0 = ntb * 64;
    int kbase = kc * 1920;
    f32x4 acc[4] = {};
    const f16* ap = a16 + (size_t)(16 * w + lm) * FLAT + kbase + 8 * g;

    for (int ks = 0; ks < 60; ++ks) {
        int k0 = kbase + ks * 32;
        // stage w1[k0:k0+32][n0:n0+64] fp32 -> fp16, transposed [n][k] in LDS
#pragma unroll
        for (int ii = 0; ii < 2; ++ii) {
            int lin = ii * 256 + tid;
            int kk = lin >> 4;
            int nn = (lin & 15) * 4;
            int ng = n0 + nn;
            const float* wp = w1 + (size_t)(k0 + kk) * D1 + ng;
            float vx, vy, vz, vw;
            if (ng + 3 < D1) { float4 v = *(const float4*)wp; vx = v.x; vy = v.y; vz = v.z; vw = v.w; }
            else {
                vx = ng     < D1 ? wp[0] : 0.f;
                vy = ng + 1 < D1 ? wp[1] : 0.f;
                vz = ng + 2 < D1 ? wp[2] : 0.f;
                vw = ng + 3 < D1 ? wp[3] : 0.f;
            }
            bstage[(nn    ) * 40 + kk] = (f16)vx;
            bstage[(nn + 1) * 40 + kk] = (f16)vy;
            bstage[(nn + 2) * 40 + kk] = (f16)vz;
            bstage[(nn + 3) * 40 + kk] = (f16)vw;
        }
        __syncthreads();
        f16x8 a = *(const f16x8*)(ap + ks * 32);
#pragma unroll
        for (int nt = 0; nt < 4; ++nt) {
            f16x8 bf = *(const f16x8*)(&bstage[(nt * 16 + lm) * 40 + 8 * g]);
            acc[nt] = __builtin_amdgcn_mfma_f32_16x16x32_f16(a, bf, acc[nt], 0, 0, 0);
        }
        __syncthreads();
    }
#pragma unroll
    for (int nt = 0; nt < 4; ++nt) {
        int n = n0 + nt * 16 + lm;
        if (n < D1) {
#pragma unroll
            for (int j = 0; j < 4; ++j) {
                int bb = 16 * w + 4 * g + j;
                part[((size_t)kc * B_ + bb) * D1 + n] = acc[nt][j];
            }
        }
    }
}

// ---------------- fc2: reduce partials, relu, @w2 + b2, sigmoid ----------------
// grid 64 (batch), 384 thr
__global__ __launch_bounds__(384) void k_fc2(const float* __restrict__ part,
                                             const float* __restrict__ b1,
                                             const float* __restrict__ w2,
                                             const float* __restrict__ b2,
                                             float* __restrict__ out) {
    int b = blockIdx.x;
    int tid = threadIdx.x;
    __shared__ float y1f[D1];
    for (int n = tid; n < D1; n += 384) {
        float s = b1[n];
#pragma unroll
        for (int kc = 0; kc < 25; ++kc) s += part[((size_t)kc * B_ + b) * D1 + n];
        y1f[n] = s > 0.f ? s : 0.f;
    }
    __syncthreads();
    if (tid < D2) {
        float acc = b2[tid];
#pragma unroll 4
        for (int n = 0; n < D1; ++n) acc += y1f[n] * w2[n * D2 + tid];
        out[b * D2 + tid] = 1.f / (1.f + __expf(-acc));
    }
}

// ---------------- launch ----------------
extern "C" void kernel_launch(void* const* d_in, const int* in_sizes, int n_in,
                              void* d_out, int out_size, void* d_ws, size_t ws_size,
                              hipStream_t stream) {
    const float* inp   = (const float*)d_in[0];
    const float* convw = (const float*)d_in[1];
    const float* convb = (const float*)d_in[2];
    const float* fwk   = (const float*)d_in[3];
    const float* fwrk  = (const float*)d_in[4];
    const float* fwb   = (const float*)d_in[5];
    const float* bwk   = (const float*)d_in[6];
    const float* bwrk  = (const float*)d_in[7];
    const float* bwb   = (const float*)d_in[8];
    const float* w1    = (const float*)d_in[9];
    const float* b1    = (const float*)d_in[10];
    const float* w2    = (const float*)d_in[11];
    const float* b2    = (const float*)d_in[12];
    float* out = (float*)d_out;

    char* ws = (char*)d_ws;
    size_t off = 0;
    auto alloc = [&](size_t bytes) { size_t o = off; off += (bytes + 255) & ~(size_t)255; return o; };
    f16*   in16  = (f16*)(ws + alloc((size_t)B_ * TIN * CIN * 2));
    f16*   wswz  = (f16*)(ws + alloc((size_t)20 * 4 * 64 * 8 * 2));
    f16*   kswz  = (f16*)(ws + alloc((size_t)2 * 60 * 10 * 64 * 8 * 2));
    f16*   rkswz = (f16*)(ws + alloc((size_t)2 * 60 * 10 * 64 * 8 * 2));
    f16*   xpool = (f16*)(ws + alloc((size_t)TPOOL * B_ * F_ * 2));
    float* mx    = (float*)(ws + alloc((size_t)2 * TPOOL * B_ * G3 * 4));
    f16*   a16   = (f16*)(ws + alloc((size_t)B_ * FLAT * 2));
    float* part  = (float*)(ws + alloc((size_t)25 * B_ * D1 * 4));
    (void)ws_size; (void)in_sizes; (void)n_in; (void)out_size;

    k_prep_in<<<dim3((B_ * TIN * CIN + 255) / 256), 256, 0, stream>>>(inp, in16);
    k_prep_w<<<dim3((20 * 4 * 64 * 8 + 255) / 256), 256, 0, stream>>>(convw, wswz);
    k_prep_k<<<dim3((2 * 60 * 10 * 64 * 8 + 255) / 256), 256, 0, stream>>>(fwk, bwk, kswz);
    k_prep_k<<<dim3((2 * 60 * 10 * 64 * 8 + 255) / 256), 256, 0, stream>>>(fwrk, bwrk, rkswz);
    k_conv<<<dim3(19, 64, 5), 256, 0, stream>>>(in16, wswz, convb, xpool);
    k_mx<<<dim3(75, 15, 2), 256, 0, stream>>>(xpool, kswz, fwb, bwb, mx);
    k_gru<<<dim3(8), 1024, 0, stream>>>(rkswz, mx, fwb, bwb, a16);
    k_fc1<<<dim3(25, 32), 256, 0, stream>>>(a16, w1, part);
    k_fc2<<<dim3(64), 384, 0, stream>>>(part, b1, w2, b2, out);
}